// Round 5
// baseline (1366.666 us; speedup 1.0000x reference)
//
#include <hip/hip_runtime.h>

#define B_  32
#define E_  512
#define HW_ 256
#define S_  257
#define NH_ 8
#define HD_ 64
#define EC_ 16
#define NCH_ 32         // E_/EC_
#define NB_ 1024        // persistent grid: 4 blocks/CU on 256 CUs
#define NT_ 256

__device__ __forceinline__ float wave_reduce(float v) {
  #pragma unroll
  for (int o = 32; o > 0; o >>= 1) v += __shfl_down(v, o, 64);
  return v;
}

// Device-scope grid barrier. bar[0]=count, bar[1]=generation (zeroed by memset
// each launch). __threadfence() on gfx950 emits buffer_wbl2 (L2 writeback) and
// the agent-scope acquire load emits buffer_inv -- cross-XCD safe.
__device__ __forceinline__ void gsync(unsigned* bar, int tid) {
  __syncthreads();
  if (tid == 0) {
    __threadfence();
    unsigned g = __hip_atomic_load(bar + 1, __ATOMIC_ACQUIRE, __HIP_MEMORY_SCOPE_AGENT);
    unsigned v = __hip_atomic_fetch_add(bar, 1u, __ATOMIC_ACQ_REL, __HIP_MEMORY_SCOPE_AGENT);
    if (v == NB_ - 1) {
      __hip_atomic_store(bar, 0u, __ATOMIC_RELAXED, __HIP_MEMORY_SCOPE_AGENT);
      __hip_atomic_fetch_add(bar + 1, 1u, __ATOMIC_ACQ_REL, __HIP_MEMORY_SCOPE_AGENT);
    } else {
      while (__hip_atomic_load(bar + 1, __ATOMIC_ACQUIRE, __HIP_MEMORY_SCOPE_AGENT) == g)
        __builtin_amdgcn_s_sleep(2);
    }
  }
  __syncthreads();
}

__device__ __forceinline__ void block_softmax257(float* l, float* red, int t) {
  float v = l[t];
  float v256 = l[256];
  red[t] = v; __syncthreads();
  #pragma unroll
  for (int s = 128; s > 0; s >>= 1) { if (t < s) red[t] = fmaxf(red[t], red[t + s]); __syncthreads(); }
  float M = fmaxf(red[0], v256);
  __syncthreads();
  float ex = expf(v - M);
  float e256 = expf(v256 - M);
  red[t] = ex; __syncthreads();
  #pragma unroll
  for (int s = 128; s > 0; s >>= 1) { if (t < s) red[t] += red[t + s]; __syncthreads(); }
  float inv = 1.f / (red[0] + e256);
  __syncthreads();
  l[t] = ex * inv;
  if (t == 0) l[256] = e256 * inv;
  __syncthreads();
}

// wave computes one complex dot of length E_ (float4 loads), returns on lane 0
__device__ __forceinline__ void cdot512(const float* ar_, const float* ai_,
                                        const float* br_, const float* bi_,
                                        int lane, float& or_, float& oi_) {
  const float4* a4 = (const float4*)ar_;
  const float4* c4 = (const float4*)ai_;
  const float4* w4 = (const float4*)br_;
  const float4* v4 = (const float4*)bi_;
  float sr = 0.f, si = 0.f;
  #pragma unroll
  for (int j = 0; j < 2; ++j) {
    int idx = lane * 2 + j;
    float4 Xr = a4[idx], Xi = c4[idx], Wr = w4[idx], Wi = v4[idx];
    sr += Xr.x * Wr.x - Xi.x * Wi.x;  si += Xr.x * Wi.x + Xi.x * Wr.x;
    sr += Xr.y * Wr.y - Xi.y * Wi.y;  si += Xr.y * Wi.y + Xi.y * Wr.y;
    sr += Xr.z * Wr.z - Xi.z * Wi.z;  si += Xr.z * Wi.z + Xi.z * Wr.z;
    sr += Xr.w * Wr.w - Xi.w * Wi.w;  si += Xr.w * Wi.w + Xi.w * Wr.w;
  }
  or_ = wave_reduce(sr); oi_ = wave_reduce(si);
}

__global__ __launch_bounds__(NT_, 4) void k_mega(
    const float* __restrict__ xr, const float* __restrict__ xi,
    const float* __restrict__ pos_r, const float* __restrict__ pos_i,
    const float* __restrict__ w_in_r, const float* __restrict__ w_in_i,
    const float* __restrict__ b_in_r, const float* __restrict__ b_in_i,
    const float* __restrict__ w_out_r, const float* __restrict__ w_out_i,
    const float* __restrict__ b_out_r, const float* __restrict__ b_out_i,
    const float* __restrict__ w_p_r, const float* __restrict__ w_p_i,
    const float* __restrict__ b_p_r, const float* __restrict__ b_p_i,
    float* __restrict__ out, int interleaved,
    unsigned* __restrict__ bar,
    float* __restrict__ mr, float* __restrict__ mi,
    float* __restrict__ ur, float* __restrict__ ui,
    float* __restrict__ p0, float* __restrict__ part, float* __restrict__ w2,
    float* __restrict__ zr_, float* __restrict__ zi_,
    float* __restrict__ a0r, float* __restrict__ a0i,
    float* __restrict__ aor, float* __restrict__ aoi) {
  __shared__ float sm[4112];                 // 16.4 KB, reused per phase
  int t = threadIdx.x, blk = blockIdx.x;
  int l = t & 63, w = t >> 6;

  // ---- P1: m[b,e] = mean_s x[b,e,s] + pos[e,0].  4096 waves x 4 rows ----
  #pragma unroll
  for (int r = 0; r < 4; ++r) {
    int wid = (blk << 2) + w + (r << 12);
    int e = wid & (E_ - 1);
    const float4* pr = (const float4*)(xr + (size_t)wid * HW_);
    const float4* pi = (const float4*)(xi + (size_t)wid * HW_);
    float4 a = pr[l], c = pi[l];
    float sr = (a.x + a.y) + (a.z + a.w);
    float si = (c.x + c.y) + (c.z + c.w);
    sr = wave_reduce(sr); si = wave_reduce(si);
    if (l == 0) {
      mr[wid] = sr * (1.f / HW_) + pos_r[(size_t)e * S_];
      mi[wid] = si * (1.f / HW_) + pos_i[(size_t)e * S_];
    }
  }
  gsync(bar, t);

  // ---- P2: q0 + u + mean-token logit.  blk < 256 -> (b,h) ----
  if (blk < B_ * NH_) {
    int bh = blk, b = bh >> 3, h = bh & 7;
    float* m_r = sm;            // 512
    float* m_i = sm + 512;      // 512
    float* p_r = sm + 1024;     // 64*5
    float* p_i = sm + 1344;     // 64*5
    float* q_r = sm + 1664;     // 64
    float* q_i = sm + 1728;     // 64
    float* red = sm + 1792;     // 256
    {
      const float4* a = (const float4*)(mr + (size_t)b * E_);
      const float4* c = (const float4*)(mi + (size_t)b * E_);
      if (t < 128) ((float4*)m_r)[t] = a[t];
      else         ((float4*)m_i)[t - 128] = c[t - 128];
    }
    __syncthreads();
    { // q0 partials: f = h*64 + fl, 4-way split over e
      int fl = t >> 2, sub = t & 3;
      int f = h * HD_ + fl;
      const float4* wr4 = (const float4*)(w_in_r + (size_t)f * E_);
      const float4* wi4 = (const float4*)(w_in_i + (size_t)f * E_);
      const float4* xr4 = (const float4*)m_r;
      const float4* xi4 = (const float4*)m_i;
      float sr = 0.f, si = 0.f;
      #pragma unroll
      for (int j = 0; j < 32; ++j) {
        int idx = sub * 32 + j;
        float4 Wr = wr4[idx], Wi = wi4[idx], Xr = xr4[idx], Xi = xi4[idx];
        sr += Xr.x * Wr.x - Xi.x * Wi.x;  si += Xr.x * Wi.x + Xi.x * Wr.x;
        sr += Xr.y * Wr.y - Xi.y * Wi.y;  si += Xr.y * Wi.y + Xi.y * Wr.y;
        sr += Xr.z * Wr.z - Xi.z * Wi.z;  si += Xr.z * Wi.z + Xi.z * Wr.z;
        sr += Xr.w * Wr.w - Xi.w * Wi.w;  si += Xr.w * Wi.w + Xi.w * Wr.w;
      }
      p_r[fl * 5 + sub] = sr; p_i[fl * 5 + sub] = si;
    }
    __syncthreads();
    if (t < HD_) {
      float s = p_r[t * 5] + p_r[t * 5 + 1] + p_r[t * 5 + 2] + p_r[t * 5 + 3];
      q_r[t] = (s + b_in_r[h * HD_ + t]) * 0.125f;
    } else if (t < 2 * HD_) {
      int d = t - HD_;
      float s = p_i[d * 5] + p_i[d * 5 + 1] + p_i[d * 5 + 2] + p_i[d * 5 + 3];
      q_i[d] = (s + b_in_i[h * HD_ + d]) * 0.125f;
    }
    __syncthreads();
    // u[e] for e = t, t+256
    float u0r = 0.f, u0i = 0.f, u1r = 0.f, u1i = 0.f;
    #pragma unroll 8
    for (int d = 0; d < HD_; ++d) {
      float qr = q_r[d], qi = q_i[d];
      const float* Wr = w_in_r + (size_t)(E_ + h * HD_ + d) * E_;
      const float* Wi = w_in_i + (size_t)(E_ + h * HD_ + d) * E_;
      float a0 = Wr[t], b0 = Wi[t], a1 = Wr[t + 256], b1 = Wi[t + 256];
      u0r += qr * a0 - qi * b0;  u0i += qr * b0 + qi * a0;
      u1r += qr * a1 - qi * b1;  u1i += qr * b1 + qi * a1;
    }
    ur[(size_t)bh * E_ + t]       = u0r;  ui[(size_t)bh * E_ + t]       = u0i;
    ur[(size_t)bh * E_ + t + 256] = u1r;  ui[(size_t)bh * E_ + t + 256] = u1i;
    // mean-token logit p0[bh] = sum_e m[e]*u[e]
    float pr_ = m_r[t] * u0r - m_i[t] * u0i + m_r[t + 256] * u1r - m_i[t + 256] * u1i;
    float pi_ = m_r[t] * u0i + m_i[t] * u0r + m_r[t + 256] * u1i + m_i[t + 256] * u1r;
    red[t] = pr_; __syncthreads();
    #pragma unroll
    for (int s = 128; s > 0; s >>= 1) { if (t < s) red[t] += red[t + s]; __syncthreads(); }
    if (t == 0) p0[bh * 2] = red[0];
    __syncthreads();
    red[t] = pi_; __syncthreads();
    #pragma unroll
    for (int s = 128; s > 0; s >>= 1) { if (t < s) red[t] += red[t + s]; __syncthreads(); }
    if (t == 0) p0[bh * 2 + 1] = red[0];
  }
  gsync(bar, t);

  // ---- P3: partial logits.  blk -> (b, chunk), exactly 32*32 = 1024 ----
  {
    int b = blk >> 5, c = blk & 31;
    int e0 = c * EC_;
    float* us = sm;                          // [EC_][NH_][2] = 256 floats
    if (t < EC_ * NH_) {
      int e = t >> 3, h = t & 7;
      us[(e * NH_ + h) * 2 + 0] = ur[(size_t)(b * NH_ + h) * E_ + e0 + e];
      us[(e * NH_ + h) * 2 + 1] = ui[(size_t)(b * NH_ + h) * E_ + e0 + e];
    }
    __syncthreads();
    float ar[NH_], ai[NH_];
    #pragma unroll
    for (int h = 0; h < NH_; ++h) { ar[h] = 0.f; ai[h] = 0.f; }
    const float* xrb = xr + ((size_t)b * E_ + e0) * HW_;
    const float* xib = xi + ((size_t)b * E_ + e0) * HW_;
    #pragma unroll 2
    for (int e = 0; e < EC_; ++e) {
      float Xr = xrb[e * HW_ + t] + pos_r[(size_t)(e0 + e) * S_ + t + 1];
      float Xi = xib[e * HW_ + t] + pos_i[(size_t)(e0 + e) * S_ + t + 1];
      #pragma unroll
      for (int h = 0; h < NH_; ++h) {
        float Ur = us[(e * NH_ + h) * 2], Ui = us[(e * NH_ + h) * 2 + 1];
        ar[h] += Xr * Ur - Xi * Ui;
        ai[h] += Xr * Ui + Xi * Ur;
      }
    }
    float2* p2 = (float2*)part;
    #pragma unroll
    for (int h = 0; h < NH_; ++h) {
      float2 v; v.x = ar[h]; v.y = ai[h];
      p2[((size_t)(b * NH_ + h) * NCH_ + c) * 256 + t] = v;
    }
  }
  gsync(bar, t);

  // ---- P4: reduce partials + dual softmax.  blk < 256 -> bh ----
  if (blk < B_ * NH_) {
    int bh = blk;
    float* lr  = sm;          // 257 (+pad)
    float* li  = sm + 260;    // 257
    float* red = sm + 520;    // 256
    const float2* p2 = (const float2*)part + (size_t)bh * NCH_ * 256;
    float sr = 0.f, si = 0.f;
    #pragma unroll 8
    for (int c = 0; c < NCH_; ++c) { float2 v = p2[c * 256 + t]; sr += v.x; si += v.y; }
    lr[t + 1] = sr; li[t + 1] = si;
    if (t == 0) { lr[0] = p0[bh * 2]; li[0] = p0[bh * 2 + 1]; }
    __syncthreads();
    block_softmax257(lr, red, t);
    block_softmax257(li, red, t);
    float2* o = (float2*)w2 + (size_t)bh * S_;
    float2 v; v.x = lr[t]; v.y = li[t]; o[t] = v;
    if (t == 0) { float2 v2; v2.x = lr[256]; v2.y = li[256]; o[256] = v2; }
  }
  gsync(bar, t);

  // ---- P5: z[b,h,e].  blk -> (b, g2), waves split k; 2 column-groups each ----
  {
    int b = blk >> 5, g2 = blk & 31;
    float2* wls = (float2*)sm;               // NH_*S_ float2 = 16.4 KB
    const float2* w2b = (const float2*)w2 + (size_t)b * NH_ * S_;
    for (int i = t; i < NH_ * S_; i += NT_) wls[i] = w2b[i];
    __syncthreads();
    #pragma unroll
    for (int gg = 0; gg < 2; ++gg) {
      int g = g2 + gg * 32;
      #pragma unroll
      for (int r = 0; r < 2; ++r) {
        int e = g * 8 + w * 2 + r;
        const float* xre = xr + ((size_t)b * E_ + e) * HW_;
        const float* xie = xi + ((size_t)b * E_ + e) * HW_;
        const float* pre = pos_r + (size_t)e * S_;
        const float* pie = pos_i + (size_t)e * S_;
        float ar[NH_], ai[NH_];
        #pragma unroll
        for (int h = 0; h < NH_; ++h) { ar[h] = 0.f; ai[h] = 0.f; }
        #pragma unroll
        for (int j = 0; j < 4; ++j) {
          int k = 1 + l + 64 * j;
          float Xr = xre[k - 1] + pre[k];
          float Xi = xie[k - 1] + pie[k];
          #pragma unroll
          for (int h = 0; h < NH_; ++h) {
            float2 W = wls[h * S_ + k];
            ar[h] += W.x * Xr - W.y * Xi;
            ai[h] += W.x * Xi + W.y * Xr;
          }
        }
        #pragma unroll
        for (int h = 0; h < NH_; ++h) { ar[h] = wave_reduce(ar[h]); ai[h] = wave_reduce(ai[h]); }
        if (l == 0) {
          float X0r = mr[b * E_ + e];
          float X0i = mi[b * E_ + e];
          #pragma unroll
          for (int h = 0; h < NH_; ++h) {
            float2 W0 = wls[h * S_];
            zr_[(size_t)(b * NH_ + h) * E_ + e] = ar[h] + W0.x * X0r - W0.y * X0i;
            zi_[(size_t)(b * NH_ + h) * E_ + e] = ai[h] + W0.x * X0i + W0.y * X0r;
          }
        }
      }
    }
  }
  gsync(bar, t);

  // ---- P6: attn0 = W_v . z + b_v*(1+i).  wave per (b,f), 4 each ----
  #pragma unroll
  for (int r = 0; r < 4; ++r) {
    int wid = (blk << 2) + w + (r << 12);
    int b = wid >> 9, f = wid & (E_ - 1), h = f >> 6;
    float sr, si;
    cdot512(zr_ + (size_t)(b * NH_ + h) * E_, zi_ + (size_t)(b * NH_ + h) * E_,
            w_in_r + (size_t)(2 * E_ + f) * E_, w_in_i + (size_t)(2 * E_ + f) * E_,
            l, sr, si);
    if (l == 0) {
      float bvr = b_in_r[2 * E_ + f], bvi = b_in_i[2 * E_ + f];
      a0r[wid] = sr + (bvr - bvi);
      a0i[wid] = si + (bvr + bvi);
    }
  }
  gsync(bar, t);

  // ---- P7: aor = W_out . attn0 + b_out ----
  #pragma unroll
  for (int r = 0; r < 4; ++r) {
    int wid = (blk << 2) + w + (r << 12);
    int b = wid >> 9, f = wid & (E_ - 1);
    float sr, si;
    cdot512(a0r + (size_t)b * E_, a0i + (size_t)b * E_,
            w_out_r + (size_t)f * E_, w_out_i + (size_t)f * E_, l, sr, si);
    if (l == 0) { aor[wid] = sr + b_out_r[f]; aoi[wid] = si + b_out_i[f]; }
  }
  gsync(bar, t);

  // ---- P8: out = W_p . aor + b_p  (interleaved complex64) ----
  #pragma unroll
  for (int r = 0; r < 4; ++r) {
    int wid = (blk << 2) + w + (r << 12);
    int b = wid >> 9, f = wid & (E_ - 1);
    float sr, si;
    cdot512(aor + (size_t)b * E_, aoi + (size_t)b * E_,
            w_p_r + (size_t)f * E_, w_p_i + (size_t)f * E_, l, sr, si);
    if (l == 0) {
      float rr = sr + b_p_r[f];
      float im = si + b_p_i[f];
      if (interleaved) { out[(size_t)wid * 2] = rr; out[(size_t)wid * 2 + 1] = im; }
      else             { out[wid] = rr; }
    }
  }
}

extern "C" void kernel_launch(void* const* d_in, const int* in_sizes, int n_in,
                              void* d_out, int out_size, void* d_ws, size_t ws_size,
                              hipStream_t stream) {
  (void)in_sizes; (void)n_in; (void)ws_size;
  const float* xr      = (const float*)d_in[0];
  const float* xi      = (const float*)d_in[1];
  const float* pos_r   = (const float*)d_in[2];
  const float* pos_i   = (const float*)d_in[3];
  const float* w_in_r  = (const float*)d_in[4];
  const float* w_in_i  = (const float*)d_in[5];
  const float* b_in_r  = (const float*)d_in[6];
  const float* b_in_i  = (const float*)d_in[7];
  const float* w_out_r = (const float*)d_in[8];
  const float* w_out_i = (const float*)d_in[9];
  const float* b_out_r = (const float*)d_in[10];
  const float* b_out_i = (const float*)d_in[11];
  const float* w_p_r   = (const float*)d_in[12];
  const float* w_p_i   = (const float*)d_in[13];
  const float* b_p_r   = (const float*)d_in[14];
  const float* b_p_i   = (const float*)d_in[15];

  const int BE = B_ * E_, BHE = B_ * NH_ * E_;
  unsigned* bar = (unsigned*)d_ws;
  float* ws   = (float*)d_ws + 64;               // 256 B for barrier
  float* mr   = ws;
  float* mi   = mr  + BE;
  float* ur   = mi  + BE;
  float* ui   = ur  + BHE;
  float* p0   = ui  + BHE;                       // 512
  float* part = p0  + 512;                       // B*NH*NCH*256*2 = 16.8 MB
  float* w2   = part + (size_t)B_ * NH_ * NCH_ * 512;
  float* zr   = w2  + (size_t)2 * B_ * NH_ * S_;
  float* zi   = zr  + BHE;
  float* a0r  = zi  + BHE;
  float* a0i  = a0r + BE;
  float* aor  = a0i + BE;
  float* aoi  = aor + BE;

  hipMemsetAsync(bar, 0, 256, stream);           // zero barrier state (capture-legal)
  k_mega<<<NB_, NT_, 0, stream>>>(
      xr, xi, pos_r, pos_i, w_in_r, w_in_i, b_in_r, b_in_i,
      w_out_r, w_out_i, b_out_r, b_out_i, w_p_r, w_p_i, b_p_r, b_p_i,
      (float*)d_out, out_size >= 2 * B_ * E_,
      bar, mr, mi, ur, ui, p0, part, w2, zr, zi, a0r, a0i, aor, aoi);
}

// Round 6
// 201.094 us; speedup vs baseline: 6.7961x; 6.7961x over previous
//
#include <hip/hip_runtime.h>

#define B_  32
#define E_  512
#define HW_ 256
#define S_  257
#define NH_ 8
#define HD_ 64
#define EC_ 32
#define NCH_ (E_ / EC_)   // 16

__device__ __forceinline__ float wave_reduce(float v) {
  #pragma unroll
  for (int o = 32; o > 0; o >>= 1) v += __shfl_down(v, o, 64);
  return v;
}

// ---- K1: m[b,e] = mean_s x[b,e,s] + pos[e,0]  (wave per row, float4 loads) ----
__global__ void k_mean(const float* __restrict__ xr, const float* __restrict__ xi,
                       const float* __restrict__ pos_r, const float* __restrict__ pos_i,
                       float* __restrict__ mr, float* __restrict__ mi) {
  int wid  = (blockIdx.x * blockDim.x + threadIdx.x) >> 6;   // [0, B*E)
  int lane = threadIdx.x & 63;
  int e = wid & (E_ - 1);
  const float4* pr = (const float4*)(xr + (size_t)wid * HW_);
  const float4* pi = (const float4*)(xi + (size_t)wid * HW_);
  float4 a = pr[lane], c = pi[lane];
  float sr = (a.x + a.y) + (a.z + a.w);
  float si = (c.x + c.y) + (c.z + c.w);
  sr = wave_reduce(sr); si = wave_reduce(si);
  if (lane == 0) {
    mr[wid] = sr * (1.f / HW_) + pos_r[(size_t)e * S_];
    mi[wid] = si * (1.f / HW_) + pos_i[(size_t)e * S_];
  }
}

// ---- K2: q0[b,f] = (m[b,:] . w_q[f,:] + b_q[f]) / 8  (complex) ----
__global__ void k_q0(const float* __restrict__ mr, const float* __restrict__ mi,
                     const float* __restrict__ w_in_r, const float* __restrict__ w_in_i,
                     const float* __restrict__ b_in_r, const float* __restrict__ b_in_i,
                     float* __restrict__ q0r, float* __restrict__ q0i) {
  int wid  = (blockIdx.x * blockDim.x + threadIdx.x) >> 6;   // [0, B*E)
  int lane = threadIdx.x & 63;
  int b = wid >> 9, f = wid & (E_ - 1);
  const float* wr = w_in_r + (size_t)f * E_;
  const float* wi = w_in_i + (size_t)f * E_;
  float ar = 0.f, ai = 0.f;
  #pragma unroll
  for (int e = lane; e < E_; e += 64) {
    float Xr = mr[b * E_ + e];
    float Xi = mi[b * E_ + e];
    float Cr = wr[e], Ci = wi[e];
    ar += Xr * Cr - Xi * Ci;
    ai += Xr * Ci + Xi * Cr;
  }
  ar = wave_reduce(ar); ai = wave_reduce(ai);
  if (lane == 0) {
    q0r[wid] = (ar + b_in_r[f]) * 0.125f;
    q0i[wid] = (ai + b_in_i[f]) * 0.125f;
  }
}

// ---- K3: u[b,h,e] = sum_d q0[b,h,d] * w_k[h*64+d, e]  (k-bias cancels in softmax)
//      + mean-token logit p0[bh] = m[b,:] . u[b,h,:]  (u still in registers) ----
__global__ __launch_bounds__(512) void k_u(
    const float* __restrict__ q0r, const float* __restrict__ q0i,
    const float* __restrict__ mr, const float* __restrict__ mi,
    const float* __restrict__ w_in_r, const float* __restrict__ w_in_i,
    float* __restrict__ ur, float* __restrict__ ui, float* __restrict__ p0) {
  int bh = blockIdx.x;            // [0, B*NH), layout b*NH+h
  int b = bh >> 3, h = bh & 7;
  int e = threadIdx.x;            // 512 threads
  __shared__ float qr[HD_], qi[HD_];
  __shared__ float red[512];
  if (threadIdx.x < HD_) {
    qr[threadIdx.x] = q0r[b * E_ + h * HD_ + threadIdx.x];
    qi[threadIdx.x] = q0i[b * E_ + h * HD_ + threadIdx.x];
  }
  __syncthreads();
  float ar = 0.f, ai = 0.f;
  #pragma unroll 8
  for (int d = 0; d < HD_; ++d) {
    float Wr = w_in_r[(size_t)(E_ + h * HD_ + d) * E_ + e];
    float Wi = w_in_i[(size_t)(E_ + h * HD_ + d) * E_ + e];
    ar += qr[d] * Wr - qi[d] * Wi;
    ai += qr[d] * Wi + qi[d] * Wr;
  }
  ur[(size_t)bh * E_ + e] = ar;
  ui[(size_t)bh * E_ + e] = ai;
  // p0 contribution: m[b,e] * u[b,h,e]
  float Xr = mr[b * E_ + e], Xi = mi[b * E_ + e];
  red[e] = Xr * ar - Xi * ai;
  __syncthreads();
  #pragma unroll
  for (int s = 256; s > 0; s >>= 1) { if (e < s) red[e] += red[e + s]; __syncthreads(); }
  if (e == 0) p0[bh * 2] = red[0];
  __syncthreads();
  red[e] = Xr * ai + Xi * ar;
  __syncthreads();
  #pragma unroll
  for (int s = 256; s > 0; s >>= 1) { if (e < s) red[e] += red[e + s]; __syncthreads(); }
  if (e == 0) p0[bh * 2 + 1] = red[0];
}

// ---- K4a: partial logits over e-chunks. block = (b, chunk), all 8 heads ----
__global__ __launch_bounds__(256) void k_logits(
    const float* __restrict__ xr, const float* __restrict__ xi,
    const float* __restrict__ pos_r, const float* __restrict__ pos_i,
    const float* __restrict__ ur, const float* __restrict__ ui,
    float* __restrict__ part) {
  int blk = blockIdx.x;
  int b = blk / NCH_, c = blk % NCH_;
  int t = threadIdx.x;                       // k-1 in [0,256)
  int e0 = c * EC_;
  __shared__ float us[EC_][NH_][2];          // 2 KB
  { int e = t >> 3, h = t & 7;               // EC_*NH_ == 256
    us[e][h][0] = ur[(size_t)(b * NH_ + h) * E_ + e0 + e];
    us[e][h][1] = ui[(size_t)(b * NH_ + h) * E_ + e0 + e]; }
  __syncthreads();
  float ar[NH_], ai[NH_];
  #pragma unroll
  for (int h = 0; h < NH_; ++h) { ar[h] = 0.f; ai[h] = 0.f; }
  const float* xrb = xr + ((size_t)b * E_ + e0) * HW_;
  const float* xib = xi + ((size_t)b * E_ + e0) * HW_;
  #pragma unroll 2
  for (int e = 0; e < EC_; ++e) {
    float Xr = xrb[e * HW_ + t] + pos_r[(size_t)(e0 + e) * S_ + t + 1];
    float Xi = xib[e * HW_ + t] + pos_i[(size_t)(e0 + e) * S_ + t + 1];
    #pragma unroll
    for (int h = 0; h < NH_; ++h) {
      float Ur = us[e][h][0], Ui = us[e][h][1];
      ar[h] += Xr * Ur - Xi * Ui;
      ai[h] += Xr * Ui + Xi * Ur;
    }
  }
  float2* p2 = (float2*)part;
  #pragma unroll
  for (int h = 0; h < NH_; ++h) {
    float2 v; v.x = ar[h]; v.y = ai[h];
    p2[((size_t)(b * NH_ + h) * NCH_ + c) * 256 + t] = v;
  }
}

__device__ void softmax257(float* l, float* red, int t) {
  float v = l[t];
  float v256 = l[256];
  red[t] = v; __syncthreads();
  #pragma unroll
  for (int s = 128; s > 0; s >>= 1) { if (t < s) red[t] = fmaxf(red[t], red[t + s]); __syncthreads(); }
  float M = fmaxf(red[0], v256);
  __syncthreads();
  float ex = expf(v - M);
  float e256 = expf(v256 - M);
  red[t] = ex; __syncthreads();
  #pragma unroll
  for (int s = 128; s > 0; s >>= 1) { if (t < s) red[t] += red[t + s]; __syncthreads(); }
  float inv = 1.f / (red[0] + e256);
  __syncthreads();
  l[t] = ex * inv;
  if (t == 0) l[256] = e256 * inv;
  __syncthreads();
}

// ---- K4b: reduce partials + dual softmax -> w2[bh][k]=(wr,wi) ----
__global__ __launch_bounds__(256) void k_softmax(
    const float* __restrict__ part, const float* __restrict__ p0,
    float* __restrict__ w2) {
  int bh = blockIdx.x;
  int t = threadIdx.x;
  __shared__ float lr[S_], li[S_], red[256];
  const float2* p2 = (const float2*)part + (size_t)bh * NCH_ * 256;
  float sr = 0.f, si = 0.f;
  #pragma unroll
  for (int c = 0; c < NCH_; ++c) { float2 v = p2[c * 256 + t]; sr += v.x; si += v.y; }
  lr[t + 1] = sr; li[t + 1] = si;
  if (t == 0) { lr[0] = p0[bh * 2]; li[0] = p0[bh * 2 + 1]; }
  __syncthreads();
  softmax257(lr, red, t);
  softmax257(li, red, t);
  float2* o = (float2*)w2 + (size_t)bh * S_;
  float2 v; v.x = lr[t]; v.y = li[t]; o[t] = v;
  if (t == 0) { float2 v2; v2.x = lr[256]; v2.y = li[256]; o[256] = v2; }
}

// ---- K4c: z[b,h,e] = sum_k w[b,h,k]*X[b,k,e]. wave per (b,e), lanes split k ----
__global__ __launch_bounds__(256) void k_z(
    const float* __restrict__ xr, const float* __restrict__ xi,
    const float* __restrict__ pos_r, const float* __restrict__ pos_i,
    const float* __restrict__ mr, const float* __restrict__ mi,
    const float* __restrict__ w2,
    float* __restrict__ zr_, float* __restrict__ zi_) {
  __shared__ float2 wls[NH_ * S_];           // 16.4 KB
  int t = threadIdx.x, l = t & 63, w = t >> 6;
  int b = blockIdx.x >> 6;                   // blockIdx = b*64 + g
  int g = blockIdx.x & 63;
  const float2* w2b = (const float2*)w2 + (size_t)b * NH_ * S_;
  for (int i = t; i < NH_ * S_; i += 256) wls[i] = w2b[i];
  __syncthreads();
  #pragma unroll
  for (int r = 0; r < 2; ++r) {
    int e = g * 8 + w * 2 + r;
    const float* xre = xr + ((size_t)b * E_ + e) * HW_;
    const float* xie = xi + ((size_t)b * E_ + e) * HW_;
    const float* pre = pos_r + (size_t)e * S_;
    const float* pie = pos_i + (size_t)e * S_;
    float ar[NH_], ai[NH_];
    #pragma unroll
    for (int h = 0; h < NH_; ++h) { ar[h] = 0.f; ai[h] = 0.f; }
    #pragma unroll
    for (int j = 0; j < 4; ++j) {
      int k = 1 + l + 64 * j;
      float Xr = xre[k - 1] + pre[k];
      float Xi = xie[k - 1] + pie[k];
      #pragma unroll
      for (int h = 0; h < NH_; ++h) {
        float2 W = wls[h * S_ + k];
        ar[h] += W.x * Xr - W.y * Xi;
        ai[h] += W.x * Xi + W.y * Xr;
      }
    }
    #pragma unroll
    for (int h = 0; h < NH_; ++h) { ar[h] = wave_reduce(ar[h]); ai[h] = wave_reduce(ai[h]); }
    if (l == 0) {
      float X0r = mr[b * E_ + e];            // m already includes pos col 0
      float X0i = mi[b * E_ + e];
      #pragma unroll
      for (int h = 0; h < NH_; ++h) {
        float2 W0 = wls[h * S_];
        zr_[(size_t)(b * NH_ + h) * E_ + e] = ar[h] + W0.x * X0r - W0.y * X0i;
        zi_[(size_t)(b * NH_ + h) * E_ + e] = ai[h] + W0.x * X0i + W0.y * X0r;
      }
    }
  }
}

// ---- K5: attn0[b, f=h*64+d] = w_v[f,:] . z[b,h,:] + b_v[f]*(1+i)  (float4) ----
__global__ void k_v(const float* __restrict__ zr, const float* __restrict__ zi,
                    const float* __restrict__ w_in_r, const float* __restrict__ w_in_i,
                    const float* __restrict__ b_in_r, const float* __restrict__ b_in_i,
                    float* __restrict__ a0r, float* __restrict__ a0i) {
  int wid  = (blockIdx.x * blockDim.x + threadIdx.x) >> 6;   // [0, B*E)
  int lane = threadIdx.x & 63;
  int b = wid >> 9, f = wid & (E_ - 1);
  int h = f >> 6;
  const float4* wr4 = (const float4*)(w_in_r + (size_t)(2 * E_ + f) * E_);
  const float4* wi4 = (const float4*)(w_in_i + (size_t)(2 * E_ + f) * E_);
  const float4* zr4 = (const float4*)(zr + (size_t)(b * NH_ + h) * E_);
  const float4* zi4 = (const float4*)(zi + (size_t)(b * NH_ + h) * E_);
  float ar = 0.f, ai = 0.f;
  #pragma unroll
  for (int j = 0; j < 2; ++j) {
    int idx = lane * 2 + j;
    float4 Zr = zr4[idx], Zi = zi4[idx], Wr = wr4[idx], Wi = wi4[idx];
    ar += Zr.x * Wr.x - Zi.x * Wi.x;  ai += Zr.x * Wi.x + Zi.x * Wr.x;
    ar += Zr.y * Wr.y - Zi.y * Wi.y;  ai += Zr.y * Wi.y + Zi.y * Wr.y;
    ar += Zr.z * Wr.z - Zi.z * Wi.z;  ai += Zr.z * Wi.z + Zi.z * Wr.z;
    ar += Zr.w * Wr.w - Zi.w * Wi.w;  ai += Zr.w * Wi.w + Zi.w * Wr.w;
  }
  ar = wave_reduce(ar); ai = wave_reduce(ai);
  if (lane == 0) {
    float bvr = b_in_r[2 * E_ + f], bvi = b_in_i[2 * E_ + f];
    a0r[wid] = ar + (bvr - bvi);   // sum of complex softmax weights = 1 + i
    a0i[wid] = ai + (bvr + bvi);
  }
}

// ---- K6: generic complex matvec out[b,f] = in[b,:] . w[f,:] + bias[f]  (float4) ----
__global__ void k_mv(const float* __restrict__ inr, const float* __restrict__ ini,
                     const float* __restrict__ wr_, const float* __restrict__ wi_,
                     const float* __restrict__ br_, const float* __restrict__ bi_,
                     float* __restrict__ outr, float* __restrict__ outi) {
  int wid  = (blockIdx.x * blockDim.x + threadIdx.x) >> 6;   // [0, B*E)
  int lane = threadIdx.x & 63;
  int b = wid >> 9, f = wid & (E_ - 1);
  const float4* wr4 = (const float4*)(wr_ + (size_t)f * E_);
  const float4* wi4 = (const float4*)(wi_ + (size_t)f * E_);
  const float4* ir4 = (const float4*)(inr + (size_t)b * E_);
  const float4* ii4 = (const float4*)(ini + (size_t)b * E_);
  float ar = 0.f, ai = 0.f;
  #pragma unroll
  for (int j = 0; j < 2; ++j) {
    int idx = lane * 2 + j;
    float4 Xr = ir4[idx], Xi = ii4[idx], Wr = wr4[idx], Wi = wi4[idx];
    ar += Xr.x * Wr.x - Xi.x * Wi.x;  ai += Xr.x * Wi.x + Xi.x * Wr.x;
    ar += Xr.y * Wr.y - Xi.y * Wi.y;  ai += Xr.y * Wi.y + Xi.y * Wr.y;
    ar += Xr.z * Wr.z - Xi.z * Wi.z;  ai += Xr.z * Wi.z + Xi.z * Wr.z;
    ar += Xr.w * Wr.w - Xi.w * Wi.w;  ai += Xr.w * Wi.w + Xi.w * Wr.w;
  }
  ar = wave_reduce(ar); ai = wave_reduce(ai);
  if (lane == 0) { outr[wid] = ar + br_[f]; outi[wid] = ai + bi_[f]; }
}

// ---- K7: final projection, interleaved complex64 output  (float4) ----
__global__ void k_final(const float* __restrict__ inr, const float* __restrict__ ini,
                        const float* __restrict__ wr_, const float* __restrict__ wi_,
                        const float* __restrict__ br_, const float* __restrict__ bi_,
                        float* __restrict__ out, int interleaved) {
  int wid  = (blockIdx.x * blockDim.x + threadIdx.x) >> 6;   // [0, B*OUT)
  int lane = threadIdx.x & 63;
  int b = wid >> 9, f = wid & (E_ - 1);
  const float4* wr4 = (const float4*)(wr_ + (size_t)f * E_);
  const float4* wi4 = (const float4*)(wi_ + (size_t)f * E_);
  const float4* ir4 = (const float4*)(inr + (size_t)b * E_);
  const float4* ii4 = (const float4*)(ini + (size_t)b * E_);
  float ar = 0.f, ai = 0.f;
  #pragma unroll
  for (int j = 0; j < 2; ++j) {
    int idx = lane * 2 + j;
    float4 Xr = ir4[idx], Xi = ii4[idx], Wr = wr4[idx], Wi = wi4[idx];
    ar += Xr.x * Wr.x - Xi.x * Wi.x;  ai += Xr.x * Wi.x + Xi.x * Wr.x;
    ar += Xr.y * Wr.y - Xi.y * Wi.y;  ai += Xr.y * Wi.y + Xi.y * Wr.y;
    ar += Xr.z * Wr.z - Xi.z * Wi.z;  ai += Xr.z * Wi.z + Xi.z * Wr.z;
    ar += Xr.w * Wr.w - Xi.w * Wi.w;  ai += Xr.w * Wi.w + Xi.w * Wr.w;
  }
  ar = wave_reduce(ar); ai = wave_reduce(ai);
  if (lane == 0) {
    float rr = ar + br_[f];
    float im = ai + bi_[f];
    if (interleaved) { out[(size_t)wid * 2] = rr; out[(size_t)wid * 2 + 1] = im; }
    else             { out[wid] = rr; }
  }
}

extern "C" void kernel_launch(void* const* d_in, const int* in_sizes, int n_in,
                              void* d_out, int out_size, void* d_ws, size_t ws_size,
                              hipStream_t stream) {
  (void)in_sizes; (void)n_in; (void)ws_size;
  const float* xr      = (const float*)d_in[0];
  const float* xi      = (const float*)d_in[1];
  const float* pos_r   = (const float*)d_in[2];
  const float* pos_i   = (const float*)d_in[3];
  const float* w_in_r  = (const float*)d_in[4];
  const float* w_in_i  = (const float*)d_in[5];
  const float* b_in_r  = (const float*)d_in[6];
  const float* b_in_i  = (const float*)d_in[7];
  const float* w_out_r = (const float*)d_in[8];
  const float* w_out_i = (const float*)d_in[9];
  const float* b_out_r = (const float*)d_in[10];
  const float* b_out_i = (const float*)d_in[11];
  const float* w_p_r   = (const float*)d_in[12];
  const float* w_p_i   = (const float*)d_in[13];
  const float* b_p_r   = (const float*)d_in[14];
  const float* b_p_i   = (const float*)d_in[15];

  const int BE = B_ * E_, BHE = B_ * NH_ * E_;
  float* ws   = (float*)d_ws;
  float* mr   = ws;
  float* mi   = mr  + BE;
  float* q0r  = mi  + BE;
  float* q0i  = q0r + BE;
  float* ur   = q0i + BE;
  float* ui   = ur  + BHE;
  float* p0   = ui  + BHE;                       // B*NH*2
  float* part = p0  + 512;                       // B*NH*NCH*256*2 floats (8.4 MB)
  float* w2   = part + (size_t)B_ * NH_ * NCH_ * 512;
  float* zr   = w2  + (size_t)2 * B_ * NH_ * S_;
  float* zi   = zr  + BHE;
  float* a0r  = zi  + BHE;
  float* a0i  = a0r + BE;
  float* aor  = a0i + BE;
  float* aoi  = aor + BE;

  k_mean   <<<B_ * E_ / 4,  256, 0, stream>>>(xr, xi, pos_r, pos_i, mr, mi);
  k_q0     <<<B_ * E_ / 4,  256, 0, stream>>>(mr, mi, w_in_r, w_in_i, b_in_r, b_in_i, q0r, q0i);
  k_u      <<<B_ * NH_,     512, 0, stream>>>(q0r, q0i, mr, mi, w_in_r, w_in_i, ur, ui, p0);
  k_logits <<<B_ * NCH_,    256, 0, stream>>>(xr, xi, pos_r, pos_i, ur, ui, part);
  k_softmax<<<B_ * NH_,     256, 0, stream>>>(part, p0, w2);
  k_z      <<<B_ * 64,      256, 0, stream>>>(xr, xi, pos_r, pos_i, mr, mi, w2, zr, zi);
  k_v      <<<B_ * E_ / 4,  256, 0, stream>>>(zr, zi, w_in_r, w_in_i, b_in_r, b_in_i, a0r, a0i);
  k_mv     <<<B_ * E_ / 4,  256, 0, stream>>>(a0r, a0i, w_out_r, w_out_i, b_out_r, b_out_i, aor, aoi);
  k_final  <<<B_ * E_ / 4,  256, 0, stream>>>(aor, aoi, w_p_r, w_p_i, b_p_r, b_p_i,
                                              (float*)d_out, out_size >= 2 * B_ * E_);
}

// Round 7
// 189.965 us; speedup vs baseline: 7.1943x; 1.0586x over previous
//
#include <hip/hip_runtime.h>

#define B_  32
#define E_  512
#define HW_ 256
#define S_  257
#define NH_ 8
#define HD_ 64
#define EC_ 32
#define NCH_ (E_ / EC_)   // 16

__device__ __forceinline__ float wave_reduce(float v) {
  #pragma unroll
  for (int o = 32; o > 0; o >>= 1) v += __shfl_down(v, o, 64);
  return v;
}

// ---- K1: m[b,e] = mean_s x[b,e,s] + pos[e,0]   (pos col 0 folded in here, once,
//      as a wave-uniform scalar load -- NOT a per-lane stride-1028 gather) ----
__global__ void k_mean(const float* __restrict__ xr, const float* __restrict__ xi,
                       const float* __restrict__ pos_r, const float* __restrict__ pos_i,
                       float* __restrict__ mr, float* __restrict__ mi) {
  int wid  = (blockIdx.x * blockDim.x + threadIdx.x) >> 6;   // [0, B*E)
  int lane = threadIdx.x & 63;
  int e = wid & (E_ - 1);
  const float* pr = xr + (size_t)wid * HW_;
  const float* pi = xi + (size_t)wid * HW_;
  float sr = 0.f, si = 0.f;
  #pragma unroll
  for (int j = 0; j < HW_; j += 64) { sr += pr[j + lane]; si += pi[j + lane]; }
  sr = wave_reduce(sr); si = wave_reduce(si);
  if (lane == 0) {
    mr[wid] = sr * (1.f / HW_) + pos_r[(size_t)e * S_];
    mi[wid] = si * (1.f / HW_) + pos_i[(size_t)e * S_];
  }
}

// ---- K2: q0[b,f] = (X0[b,:] . w_q[f,:] + b_q[f]) / 8  (complex), X0 = m ----
__global__ void k_q0(const float* __restrict__ mr, const float* __restrict__ mi,
                     const float* __restrict__ w_in_r, const float* __restrict__ w_in_i,
                     const float* __restrict__ b_in_r, const float* __restrict__ b_in_i,
                     float* __restrict__ q0r, float* __restrict__ q0i) {
  int wid  = (blockIdx.x * blockDim.x + threadIdx.x) >> 6;   // [0, B*E)
  int lane = threadIdx.x & 63;
  int b = wid >> 9, f = wid & (E_ - 1);
  const float* wr = w_in_r + (size_t)f * E_;
  const float* wi = w_in_i + (size_t)f * E_;
  float ar = 0.f, ai = 0.f;
  #pragma unroll
  for (int e = lane; e < E_; e += 64) {
    float Xr = mr[b * E_ + e];
    float Xi = mi[b * E_ + e];
    float Cr = wr[e], Ci = wi[e];
    ar += Xr * Cr - Xi * Ci;
    ai += Xr * Ci + Xi * Cr;
  }
  ar = wave_reduce(ar); ai = wave_reduce(ai);
  if (lane == 0) {
    q0r[wid] = (ar + b_in_r[f]) * 0.125f;
    q0i[wid] = (ai + b_in_i[f]) * 0.125f;
  }
}

// ---- K3: u[b,h,e] = sum_d q0[b,h,d] * w_k[h*64+d, e]  (k-bias cancels in softmax) ----
__global__ void k_u(const float* __restrict__ q0r, const float* __restrict__ q0i,
                    const float* __restrict__ w_in_r, const float* __restrict__ w_in_i,
                    float* __restrict__ ur, float* __restrict__ ui) {
  int bh = blockIdx.x;            // [0, B*NH), layout b*NH+h
  int b = bh >> 3, h = bh & 7;
  int e = threadIdx.x;            // 512 threads
  __shared__ float qr[HD_], qi[HD_];
  if (threadIdx.x < HD_) {
    qr[threadIdx.x] = q0r[b * E_ + h * HD_ + threadIdx.x];
    qi[threadIdx.x] = q0i[b * E_ + h * HD_ + threadIdx.x];
  }
  __syncthreads();
  float ar = 0.f, ai = 0.f;
  #pragma unroll 8
  for (int d = 0; d < HD_; ++d) {
    float Wr = w_in_r[(size_t)(E_ + h * HD_ + d) * E_ + e];
    float Wi = w_in_i[(size_t)(E_ + h * HD_ + d) * E_ + e];
    ar += qr[d] * Wr - qi[d] * Wi;
    ai += qr[d] * Wi + qi[d] * Wr;
  }
  ur[(size_t)bh * E_ + e] = ar;
  ui[(size_t)bh * E_ + e] = ai;
}

// ---- K4a: partial logits over e-chunks. block = (b, chunk), all 8 heads ----
__global__ __launch_bounds__(256) void k_logits(
    const float* __restrict__ xr, const float* __restrict__ xi,
    const float* __restrict__ pos_r, const float* __restrict__ pos_i,
    const float* __restrict__ ur, const float* __restrict__ ui,
    float* __restrict__ part) {
  int blk = blockIdx.x;
  int b = blk / NCH_, c = blk % NCH_;
  int t = threadIdx.x;                       // k-1 in [0,256)
  int e0 = c * EC_;
  __shared__ float us[EC_][NH_][2];          // 2 KB
  { int e = t >> 3, h = t & 7;               // EC_*NH_ == 256
    us[e][h][0] = ur[(size_t)(b * NH_ + h) * E_ + e0 + e];
    us[e][h][1] = ui[(size_t)(b * NH_ + h) * E_ + e0 + e]; }
  __syncthreads();
  float ar[NH_], ai[NH_];
  #pragma unroll
  for (int h = 0; h < NH_; ++h) { ar[h] = 0.f; ai[h] = 0.f; }
  const float* xrb = xr + ((size_t)b * E_ + e0) * HW_;
  const float* xib = xi + ((size_t)b * E_ + e0) * HW_;
  #pragma unroll 2
  for (int e = 0; e < EC_; ++e) {
    float Xr = xrb[e * HW_ + t] + pos_r[(size_t)(e0 + e) * S_ + t + 1];
    float Xi = xib[e * HW_ + t] + pos_i[(size_t)(e0 + e) * S_ + t + 1];
    #pragma unroll
    for (int h = 0; h < NH_; ++h) {
      float Ur = us[e][h][0], Ui = us[e][h][1];
      ar[h] += Xr * Ur - Xi * Ui;
      ai[h] += Xr * Ui + Xi * Ur;
    }
  }
  float2* p2 = (float2*)part;
  #pragma unroll
  for (int h = 0; h < NH_; ++h) {
    float2 v; v.x = ar[h]; v.y = ai[h];
    p2[((size_t)(b * NH_ + h) * NCH_ + c) * 256 + t] = v;
  }
}

__device__ void softmax257(float* l, float* red, int t) {
  float v = l[t];
  float v256 = l[256];
  red[t] = v; __syncthreads();
  #pragma unroll
  for (int s = 128; s > 0; s >>= 1) { if (t < s) red[t] = fmaxf(red[t], red[t + s]); __syncthreads(); }
  float M = fmaxf(red[0], v256);
  __syncthreads();
  float ex = expf(v - M);
  float e256 = expf(v256 - M);
  red[t] = ex; __syncthreads();
  #pragma unroll
  for (int s = 128; s > 0; s >>= 1) { if (t < s) red[t] += red[t + s]; __syncthreads(); }
  float inv = 1.f / (red[0] + e256);
  __syncthreads();
  l[t] = ex * inv;
  if (t == 0) l[256] = e256 * inv;
  __syncthreads();
}

// ---- K4b: reduce partials + mean-token logit + dual softmax -> w2[bh][k] ----
__global__ __launch_bounds__(256) void k_softmax(
    const float* __restrict__ part,
    const float* __restrict__ mr, const float* __restrict__ mi,
    const float* __restrict__ ur, const float* __restrict__ ui,
    float* __restrict__ w2) {
  int bh = blockIdx.x; int b = bh >> 3;
  int t = threadIdx.x;
  __shared__ float lr[S_], li[S_], red[256];
  const float2* p2 = (const float2*)part + (size_t)bh * NCH_ * 256;
  float sr = 0.f, si = 0.f;
  #pragma unroll
  for (int c = 0; c < NCH_; ++c) { float2 v = p2[c * 256 + t]; sr += v.x; si += v.y; }
  lr[t + 1] = sr; li[t + 1] = si;
  // mean-token logit (X0 = m, contiguous)
  const float* urb = ur + (size_t)bh * E_;
  const float* uib = ui + (size_t)bh * E_;
  float p0r = 0.f, p0i = 0.f;
  #pragma unroll
  for (int e = t; e < E_; e += 256) {
    float Xr = mr[b * E_ + e];
    float Xi = mi[b * E_ + e];
    p0r += Xr * urb[e] - Xi * uib[e];
    p0i += Xr * uib[e] + Xi * urb[e];
  }
  red[t] = p0r; __syncthreads();
  #pragma unroll
  for (int s = 128; s > 0; s >>= 1) { if (t < s) red[t] += red[t + s]; __syncthreads(); }
  if (t == 0) lr[0] = red[0];
  __syncthreads();
  red[t] = p0i; __syncthreads();
  #pragma unroll
  for (int s = 128; s > 0; s >>= 1) { if (t < s) red[t] += red[t + s]; __syncthreads(); }
  if (t == 0) li[0] = red[0];
  __syncthreads();
  softmax257(lr, red, t);
  softmax257(li, red, t);
  float2* o = (float2*)w2 + (size_t)bh * S_;
  float2 v; v.x = lr[t]; v.y = li[t]; o[t] = v;
  if (t == 0) { float2 v2; v2.x = lr[256]; v2.y = li[256]; o[256] = v2; }
}

// ---- K4c: z[b,h,e] = sum_k w[b,h,k]*X[b,k,e]. wave per (b,e), lanes split k ----
__global__ __launch_bounds__(256) void k_z(
    const float* __restrict__ xr, const float* __restrict__ xi,
    const float* __restrict__ pos_r, const float* __restrict__ pos_i,
    const float* __restrict__ mr, const float* __restrict__ mi,
    const float* __restrict__ w2,
    float* __restrict__ zr_, float* __restrict__ zi_) {
  __shared__ float2 wls[NH_ * S_];           // 16.4 KB
  int t = threadIdx.x, l = t & 63, w = t >> 6;
  int b = blockIdx.x >> 6;                   // blockIdx = b*64 + g
  int g = blockIdx.x & 63;
  const float2* w2b = (const float2*)w2 + (size_t)b * NH_ * S_;
  for (int i = t; i < NH_ * S_; i += 256) wls[i] = w2b[i];
  __syncthreads();
  #pragma unroll
  for (int r = 0; r < 2; ++r) {
    int e = g * 8 + w * 2 + r;
    const float* xre = xr + ((size_t)b * E_ + e) * HW_;
    const float* xie = xi + ((size_t)b * E_ + e) * HW_;
    const float* pre = pos_r + (size_t)e * S_;
    const float* pie = pos_i + (size_t)e * S_;
    float ar[NH_], ai[NH_];
    #pragma unroll
    for (int h = 0; h < NH_; ++h) { ar[h] = 0.f; ai[h] = 0.f; }
    #pragma unroll
    for (int j = 0; j < 4; ++j) {
      int k = 1 + l + 64 * j;
      float Xr = xre[k - 1] + pre[k];
      float Xi = xie[k - 1] + pie[k];
      #pragma unroll
      for (int h = 0; h < NH_; ++h) {
        float2 W = wls[h * S_ + k];
        ar[h] += W.x * Xr - W.y * Xi;
        ai[h] += W.x * Xi + W.y * Xr;
      }
    }
    #pragma unroll
    for (int h = 0; h < NH_; ++h) { ar[h] = wave_reduce(ar[h]); ai[h] = wave_reduce(ai[h]); }
    if (l == 0) {
      float X0r = mr[b * E_ + e];
      float X0i = mi[b * E_ + e];
      #pragma unroll
      for (int h = 0; h < NH_; ++h) {
        float2 W0 = wls[h * S_];
        zr_[(size_t)(b * NH_ + h) * E_ + e] = ar[h] + W0.x * X0r - W0.y * X0i;
        zi_[(size_t)(b * NH_ + h) * E_ + e] = ai[h] + W0.x * X0i + W0.y * X0r;
      }
    }
  }
}

// ---- K5: attn0[b, f=h*64+d] = w_v[f,:] . z[b,h,:] + b_v[f]*(1+i) ----
__global__ void k_v(const float* __restrict__ zr, const float* __restrict__ zi,
                    const float* __restrict__ w_in_r, const float* __restrict__ w_in_i,
                    const float* __restrict__ b_in_r, const float* __restrict__ b_in_i,
                    float* __restrict__ a0r, float* __restrict__ a0i) {
  int wid  = (blockIdx.x * blockDim.x + threadIdx.x) >> 6;   // [0, B*E)
  int lane = threadIdx.x & 63;
  int b = wid >> 9, f = wid & (E_ - 1);
  int h = f >> 6;
  const float* wr  = w_in_r + (size_t)(2 * E_ + f) * E_;
  const float* wi  = w_in_i + (size_t)(2 * E_ + f) * E_;
  const float* zrp = zr + (size_t)(b * NH_ + h) * E_;
  const float* zip = zi + (size_t)(b * NH_ + h) * E_;
  float ar = 0.f, ai = 0.f;
  #pragma unroll
  for (int e = lane; e < E_; e += 64) {
    float Zr = zrp[e], Zi = zip[e], Cr = wr[e], Ci = wi[e];
    ar += Zr * Cr - Zi * Ci;
    ai += Zr * Ci + Zi * Cr;
  }
  ar = wave_reduce(ar); ai = wave_reduce(ai);
  if (lane == 0) {
    float bvr = b_in_r[2 * E_ + f], bvi = b_in_i[2 * E_ + f];
    a0r[wid] = ar + (bvr - bvi);   // sum of complex softmax weights = 1 + i
    a0i[wid] = ai + (bvr + bvi);
  }
}

// ---- K6: generic complex matvec out[b,f] = in[b,:] . w[f,:] + bias[f] ----
__global__ void k_mv(const float* __restrict__ inr, const float* __restrict__ ini,
                     const float* __restrict__ wr_, const float* __restrict__ wi_,
                     const float* __restrict__ br_, const float* __restrict__ bi_,
                     float* __restrict__ outr, float* __restrict__ outi) {
  int wid  = (blockIdx.x * blockDim.x + threadIdx.x) >> 6;   // [0, B*E)
  int lane = threadIdx.x & 63;
  int b = wid >> 9, f = wid & (E_ - 1);
  const float* wr = wr_ + (size_t)f * E_;
  const float* wi = wi_ + (size_t)f * E_;
  const float* ir = inr + (size_t)b * E_;
  const float* ii = ini + (size_t)b * E_;
  float ar = 0.f, ai = 0.f;
  #pragma unroll
  for (int e = lane; e < E_; e += 64) {
    float Xr = ir[e], Xi = ii[e], Cr = wr[e], Ci = wi[e];
    ar += Xr * Cr - Xi * Ci;
    ai += Xr * Ci + Xi * Cr;
  }
  ar = wave_reduce(ar); ai = wave_reduce(ai);
  if (lane == 0) { outr[wid] = ar + br_[f]; outi[wid] = ai + bi_[f]; }
}

// ---- K7: final projection, writes interleaved complex64 output ----
__global__ void k_final(const float* __restrict__ inr, const float* __restrict__ ini,
                        const float* __restrict__ wr_, const float* __restrict__ wi_,
                        const float* __restrict__ br_, const float* __restrict__ bi_,
                        float* __restrict__ out, int interleaved) {
  int wid  = (blockIdx.x * blockDim.x + threadIdx.x) >> 6;   // [0, B*OUT)
  int lane = threadIdx.x & 63;
  int b = wid >> 9, f = wid & (E_ - 1);
  const float* wr = wr_ + (size_t)f * E_;
  const float* wi = wi_ + (size_t)f * E_;
  const float* ir = inr + (size_t)b * E_;
  const float* ii = ini + (size_t)b * E_;
  float ar = 0.f, ai = 0.f;
  #pragma unroll
  for (int e = lane; e < E_; e += 64) {
    float Xr = ir[e], Xi = ii[e], Cr = wr[e], Ci = wi[e];
    ar += Xr * Cr - Xi * Ci;
    ai += Xr * Ci + Xi * Cr;
  }
  ar = wave_reduce(ar); ai = wave_reduce(ai);
  if (lane == 0) {
    float rr = ar + br_[f];
    float im = ai + bi_[f];
    if (interleaved) { out[(size_t)wid * 2] = rr; out[(size_t)wid * 2 + 1] = im; }
    else             { out[wid] = rr; }
  }
}

extern "C" void kernel_launch(void* const* d_in, const int* in_sizes, int n_in,
                              void* d_out, int out_size, void* d_ws, size_t ws_size,
                              hipStream_t stream) {
  (void)in_sizes; (void)n_in; (void)ws_size;
  const float* xr      = (const float*)d_in[0];
  const float* xi      = (const float*)d_in[1];
  const float* pos_r   = (const float*)d_in[2];
  const float* pos_i   = (const float*)d_in[3];
  const float* w_in_r  = (const float*)d_in[4];
  const float* w_in_i  = (const float*)d_in[5];
  const float* b_in_r  = (const float*)d_in[6];
  const float* b_in_i  = (const float*)d_in[7];
  const float* w_out_r = (const float*)d_in[8];
  const float* w_out_i = (const float*)d_in[9];
  const float* b_out_r = (const float*)d_in[10];
  const float* b_out_i = (const float*)d_in[11];
  const float* w_p_r   = (const float*)d_in[12];
  const float* w_p_i   = (const float*)d_in[13];
  const float* b_p_r   = (const float*)d_in[14];
  const float* b_p_i   = (const float*)d_in[15];

  const int BE = B_ * E_, BHE = B_ * NH_ * E_;
  float* ws   = (float*)d_ws;
  float* mr   = ws;
  float* mi   = mr  + BE;
  float* q0r  = mi  + BE;
  float* q0i  = q0r + BE;
  float* ur   = q0i + BE;
  float* ui   = ur  + BHE;
  float* part = ui  + BHE;                       // B*NH*NCH*256*2 floats
  float* w2   = part + (size_t)B_ * NH_ * NCH_ * 512;
  float* zr   = w2  + (size_t)2 * B_ * NH_ * S_;
  float* zi   = zr  + BHE;
  float* a0r  = zi  + BHE;
  float* a0i  = a0r + BE;
  float* aor  = a0i + BE;
  float* aoi  = aor + BE;

  k_mean   <<<B_ * E_ / 4,  256, 0, stream>>>(xr, xi, pos_r, pos_i, mr, mi);
  k_q0     <<<B_ * E_ / 4,  256, 0, stream>>>(mr, mi, w_in_r, w_in_i, b_in_r, b_in_i, q0r, q0i);
  k_u      <<<B_ * NH_,     512, 0, stream>>>(q0r, q0i, w_in_r, w_in_i, ur, ui);
  k_logits <<<B_ * NCH_,    256, 0, stream>>>(xr, xi, pos_r, pos_i, ur, ui, part);
  k_softmax<<<B_ * NH_,     256, 0, stream>>>(part, mr, mi, ur, ui, w2);
  k_z      <<<B_ * 64,      256, 0, stream>>>(xr, xi, pos_r, pos_i, mr, mi, w2, zr, zi);
  k_v      <<<B_ * E_ / 4,  256, 0, stream>>>(zr, zi, w_in_r, w_in_i, b_in_r, b_in_i, a0r, a0i);
  k_mv     <<<B_ * E_ / 4,  256, 0, stream>>>(a0r, a0i, w_out_r, w_out_i, b_out_r, b_out_i, aor, aoi);
  k_final  <<<B_ * E_ / 4,  256, 0, stream>>>(aor, aoi, w_p_r, w_p_i, b_p_r, b_p_i,
                                              (float*)d_out, out_size >= 2 * B_ * E_);
}